// Round 5
// baseline (481.108 us; speedup 1.0000x reference)
//
#include <hip/hip_runtime.h>
#include <hip/hip_bf16.h>

// GCN encoder: z = relu(A @ relu(A @ (x@W1) + b1) @ W2 + b2)
// R10 (resubmit after infra failure): LDS-free direct-MFMA GEMMs. R9 post-
// mortem: counted vmcnt helped (70->60us) but per-step cycle model off 6x --
// the barrier'd LDS-staging structure ITSELF is the overhead for these skinny
// GEMMs. B (256KB/64KB) is L1/L2-resident; A has no cross-wave reuse when each
// wave owns 16 out-rows. So: no LDS, no barriers. Per wave: 16x128 out; A
// fragments loaded direct from global (2xfloat4 -> cvt_pk -> bf16x8, same
// element mapping as the verified LDS path), 2-deep register prefetch; B
// fragments direct (L1-hot). Waves self-pace; compiler emits precise counted
// waitcnts on reg-only pipelines. Grid bn-fastest so same-A blocks dispatch
// adjacent (L3 twin).

typedef __attribute__((ext_vector_type(8))) short bf16x8;
typedef __attribute__((ext_vector_type(4))) float f32x4;

#define NN 50000
#define NE 800000
#define NF 512
#define NH 256
#define NL 128
#define NB ((NN + 255) / 256)

static __device__ __forceinline__ unsigned short f2bf(float f) {
  union { float f; unsigned int u; } v; v.f = f;
  unsigned int r = v.u + 0x7fffu + ((v.u >> 16) & 1u);   // RNE
  return (unsigned short)(r >> 16);
}
static __device__ __forceinline__ float bf2f(unsigned short u) {
  union { unsigned int u; float f; } v; v.u = (unsigned int)u << 16;
  return v.f;
}

// HW packed f32->bf16 (RNE), 2 elems / instruction (no builtin on gfx950).
static __device__ __forceinline__ unsigned int pkbf(float lo, float hi) {
  unsigned int r;
  asm("v_cvt_pk_bf16_f32 %0, %1, %2" : "=v"(r) : "v"(lo), "v"(hi));
  return r;
}
static __device__ __forceinline__ uint4 pk8(float4 a, float4 b) {
  uint4 o;
  o.x = pkbf(a.x, a.y); o.y = pkbf(a.z, a.w);
  o.z = pkbf(b.x, b.y); o.w = pkbf(b.z, b.w);
  return o;
}

// ---------------- CSR build ----------------
extern "C" __global__ void k_hist(const int* __restrict__ rows, int* __restrict__ counts, int n) {
  int i = blockIdx.x * 256 + threadIdx.x;
  if (i < n) atomicAdd(&counts[rows[i]], 1);
}

extern "C" __global__ __launch_bounds__(256) void k_blocksum(
    const int* __restrict__ counts, int* __restrict__ bsum, int n) {
  __shared__ int s[256];
  int t = threadIdx.x;
  int i = blockIdx.x * 256 + t;
  s[t] = (i < n) ? counts[i] : 0;
  __syncthreads();
  for (int off = 128; off > 0; off >>= 1) {
    if (t < off) s[t] += s[t + off];
    __syncthreads();
  }
  if (t == 0) bsum[blockIdx.x] = s[0];
}

extern "C" __global__ __launch_bounds__(256) void k_scansums(
    const int* __restrict__ bsum, int* __restrict__ bpre, int* __restrict__ rp, int nb, int n) {
  __shared__ int s[256];
  int t = threadIdx.x;
  int v = (t < nb) ? bsum[t] : 0;
  s[t] = v;
  __syncthreads();
  for (int off = 1; off < 256; off <<= 1) {
    int u = (t >= off) ? s[t - off] : 0;
    __syncthreads();
    s[t] += u;
    __syncthreads();
  }
  if (t < nb) bpre[t] = s[t] - v;
  if (t == 255) rp[n] = s[255];
}

extern "C" __global__ __launch_bounds__(256) void k_scanfin(
    const int* __restrict__ counts, const int* __restrict__ bpre,
    int* __restrict__ rp, int* __restrict__ cur, int n) {
  __shared__ int s[256];
  int t = threadIdx.x;
  int i = blockIdx.x * 256 + t;
  int c = (i < n) ? counts[i] : 0;
  s[t] = c;
  __syncthreads();
  for (int off = 1; off < 256; off <<= 1) {
    int u = (t >= off) ? s[t - off] : 0;
    __syncthreads();
    s[t] += u;
    __syncthreads();
  }
  if (i < n) {
    int e = bpre[blockIdx.x] + s[t] - c;
    rp[i] = e;
    cur[i] = e;
  }
}

extern "C" __global__ void k_scatter(const int* __restrict__ rows, const int* __restrict__ cols,
    const float* __restrict__ vals, int* __restrict__ cur, int2* __restrict__ ep, int n) {
  int i = blockIdx.x * 256 + threadIdx.x;
  if (i < n) {
    int p = atomicAdd(&cur[rows[i]], 1);
    int2 e; e.x = cols[i]; e.y = __float_as_int(vals[i]);
    ep[p] = e;
  }
}

// ---------------- weight transpose-cast: W [K][N] fp32 -> WT [N][K] bf16 ----------------
extern "C" __global__ void k_transcast(const float* __restrict__ w, unsigned short* __restrict__ wt,
                                       int K, int N) {
  int k = blockIdx.x; int n = threadIdx.x;
  wt[(size_t)n * K + k] = f2bf(w[(size_t)k * N + n]);
}

// ---------------- GEMM1: C[NN][256] = x[NN][512](fp32) * W1T[256][512]^T, bf16 out ----------------
// LDS-free: wave w owns rows [bm+w*16, +16), cols [bn, bn+128). 8 K-steps of 64.
// A direct-from-global (fp32 -> cvt_pk), 2-deep prefetch; B direct (L1-hot).
extern "C" __global__ __launch_bounds__(256) void k_gemm1(
    const float* __restrict__ A, const unsigned short* __restrict__ BT,
    unsigned short* __restrict__ C) {
  int tid = threadIdx.x;
  int lane = tid & 63, wid = tid >> 6;
  int l15 = lane & 15, lq = lane >> 4;
  int bn = blockIdx.x * 128, bm = blockIdx.y * 64;

  int arow = bm + wid * 16 + l15; if (arow >= NN) arow = NN - 1;
  const float* ap = A + (size_t)arow * NF + lq * 8;
  const unsigned short* bp[8];
#pragma unroll
  for (int nt = 0; nt < 8; ++nt)
    bp[nt] = BT + (size_t)(bn + nt * 16 + l15) * NF + lq * 8;

  f32x4 acc[8];
#pragma unroll
  for (int i = 0; i < 8; ++i) acc[i] = (f32x4){0.f, 0.f, 0.f, 0.f};

  float4 apf[2][4];   // [set][ks*2+half] -- 2-deep A prefetch
#pragma unroll
  for (int ks = 0; ks < 2; ++ks) {
    apf[0][ks * 2 + 0] = *(const float4*)(ap + ks * 32);
    apf[0][ks * 2 + 1] = *(const float4*)(ap + ks * 32 + 4);
  }

#pragma unroll
  for (int t = 0; t < 8; ++t) {
    int k0 = t * 64;
    if (t < 7) {
#pragma unroll
      for (int ks = 0; ks < 2; ++ks) {
        apf[(t + 1) & 1][ks * 2 + 0] = *(const float4*)(ap + k0 + 64 + ks * 32);
        apf[(t + 1) & 1][ks * 2 + 1] = *(const float4*)(ap + k0 + 64 + ks * 32 + 4);
      }
    }
#pragma unroll
    for (int ks = 0; ks < 2; ++ks) {
      bf16x8 bfr[8];
#pragma unroll
      for (int nt = 0; nt < 8; ++nt)
        bfr[nt] = *(const bf16x8*)(bp[nt] + k0 + ks * 32);
      union { uint4 u; bf16x8 v; } cv;
      cv.u = pk8(apf[t & 1][ks * 2], apf[t & 1][ks * 2 + 1]);
      bf16x8 af = cv.v;
#pragma unroll
      for (int nt = 0; nt < 8; ++nt)
        acc[nt] = __builtin_amdgcn_mfma_f32_16x16x32_bf16(af, bfr[nt], acc[nt], 0, 0, 0);
    }
  }

#pragma unroll
  for (int nt = 0; nt < 8; ++nt) {
#pragma unroll
    for (int r = 0; r < 4; ++r) {
      int gr = bm + wid * 16 + lq * 4 + r;
      if (gr < NN) {
        int gc = bn + nt * 16 + l15;
        C[(size_t)gr * NH + gc] = f2bf(acc[nt][r]);
      }
    }
  }
}

// ---------------- GEMM2: C[NN][128] = h[NN][256](bf16) * W2T[128][256]^T, bf16 out ----------------
// Same LDS-free skeleton; A already bf16 (no cvt). 4 K-steps; full N=128 per block.
extern "C" __global__ __launch_bounds__(256) void k_gemm2(
    const unsigned short* __restrict__ Ah, const unsigned short* __restrict__ BT,
    unsigned short* __restrict__ C) {
  int tid = threadIdx.x;
  int lane = tid & 63, wid = tid >> 6;
  int l15 = lane & 15, lq = lane >> 4;
  int bm = blockIdx.x * 64;

  int arow = bm + wid * 16 + l15; if (arow >= NN) arow = NN - 1;
  const unsigned short* ap = Ah + (size_t)arow * NH + lq * 8;
  const unsigned short* bp[8];
#pragma unroll
  for (int nt = 0; nt < 8; ++nt)
    bp[nt] = BT + (size_t)(nt * 16 + l15) * NH + lq * 8;

  f32x4 acc[8];
#pragma unroll
  for (int i = 0; i < 8; ++i) acc[i] = (f32x4){0.f, 0.f, 0.f, 0.f};

  bf16x8 apf[2][2];   // [set][ks] -- 2-deep A prefetch
#pragma unroll
  for (int ks = 0; ks < 2; ++ks)
    apf[0][ks] = *(const bf16x8*)(ap + ks * 32);

#pragma unroll
  for (int t = 0; t < 4; ++t) {
    int k0 = t * 64;
    if (t < 3) {
#pragma unroll
      for (int ks = 0; ks < 2; ++ks)
        apf[(t + 1) & 1][ks] = *(const bf16x8*)(ap + k0 + 64 + ks * 32);
    }
#pragma unroll
    for (int ks = 0; ks < 2; ++ks) {
      bf16x8 bfr[8];
#pragma unroll
      for (int nt = 0; nt < 8; ++nt)
        bfr[nt] = *(const bf16x8*)(bp[nt] + k0 + ks * 32);
      bf16x8 af = apf[t & 1][ks];
#pragma unroll
      for (int nt = 0; nt < 8; ++nt)
        acc[nt] = __builtin_amdgcn_mfma_f32_16x16x32_bf16(af, bfr[nt], acc[nt], 0, 0, 0);
    }
  }

#pragma unroll
  for (int nt = 0; nt < 8; ++nt) {
#pragma unroll
    for (int r = 0; r < 4; ++r) {
      int gr = bm + wid * 16 + lq * 4 + r;
      if (gr < NN) {
        int gc = nt * 16 + l15;
        C[(size_t)gr * NL + gc] = f2bf(acc[nt][r]);
      }
    }
  }
}

// ---------------- SpMM (CSR row-gather), bf16 src, unroll-8/4/1, fused bias+relu ----------------
extern "C" __global__ __launch_bounds__(256) void k_spmm256(
    const int* __restrict__ rp, const int2* __restrict__ ep,
    const unsigned short* __restrict__ src, const float* __restrict__ bias,
    ushort4* __restrict__ out) {
  int row = blockIdx.x * 4 + (threadIdx.x >> 6);
  int lane = threadIdx.x & 63;
  if (row >= NN) return;
  int e0 = __builtin_amdgcn_readfirstlane(rp[row]);
  int e1 = __builtin_amdgcn_readfirstlane(rp[row + 1]);
  const ushort4* srcv = (const ushort4*)src;
  float4 acc = {0.f, 0.f, 0.f, 0.f};
  int e = e0;
  for (; e + 8 <= e1; e += 8) {
    int2 p[8]; ushort4 g[8];
#pragma unroll
    for (int j = 0; j < 8; ++j) p[j] = ep[e + j];
#pragma unroll
    for (int j = 0; j < 8; ++j) g[j] = srcv[(size_t)p[j].x * (NH / 4) + lane];
#pragma unroll
    for (int j = 0; j < 8; ++j) {
      float v = __int_as_float(p[j].y);
      acc.x = fmaf(v, bf2f(g[j].x), acc.x); acc.y = fmaf(v, bf2f(g[j].y), acc.y);
      acc.z = fmaf(v, bf2f(g[j].z), acc.z); acc.w = fmaf(v, bf2f(g[j].w), acc.w);
    }
  }
  for (; e + 4 <= e1; e += 4) {
    int2 p[4]; ushort4 g[4];
#pragma unroll
    for (int j = 0; j < 4; ++j) p[j] = ep[e + j];
#pragma unroll
    for (int j = 0; j < 4; ++j) g[j] = srcv[(size_t)p[j].x * (NH / 4) + lane];
#pragma unroll
    for (int j = 0; j < 4; ++j) {
      float v = __int_as_float(p[j].y);
      acc.x = fmaf(v, bf2f(g[j].x), acc.x); acc.y = fmaf(v, bf2f(g[j].y), acc.y);
      acc.z = fmaf(v, bf2f(g[j].z), acc.z); acc.w = fmaf(v, bf2f(g[j].w), acc.w);
    }
  }
  for (; e < e1; ++e) {
    int2 p = ep[e];
    float v = __int_as_float(p.y);
    ushort4 g = srcv[(size_t)p.x * (NH / 4) + lane];
    acc.x = fmaf(v, bf2f(g.x), acc.x); acc.y = fmaf(v, bf2f(g.y), acc.y);
    acc.z = fmaf(v, bf2f(g.z), acc.z); acc.w = fmaf(v, bf2f(g.w), acc.w);
  }
  float4 b = ((const float4*)bias)[lane];
  ushort4 o;
  o.x = f2bf(fmaxf(acc.x + b.x, 0.f));
  o.y = f2bf(fmaxf(acc.y + b.y, 0.f));
  o.z = f2bf(fmaxf(acc.z + b.z, 0.f));
  o.w = f2bf(fmaxf(acc.w + b.w, 0.f));
  out[(size_t)row * (NH / 4) + lane] = o;
}

extern "C" __global__ __launch_bounds__(256) void k_spmm128(
    const int* __restrict__ rp, const int2* __restrict__ ep,
    const unsigned short* __restrict__ src, const float* __restrict__ bias,
    float2* __restrict__ out) {
  int row = blockIdx.x * 4 + (threadIdx.x >> 6);
  int lane = threadIdx.x & 63;
  if (row >= NN) return;
  int e0 = __builtin_amdgcn_readfirstlane(rp[row]);
  int e1 = __builtin_amdgcn_readfirstlane(rp[row + 1]);
  const ushort2* srcv = (const ushort2*)src;
  float2 acc = {0.f, 0.f};
  int e = e0;
  for (; e + 8 <= e1; e += 8) {
    int2 p[8]; ushort2 g[8];
#pragma unroll
    for (int j = 0; j < 8; ++j) p[j] = ep[e + j];
#pragma unroll
    for (int j = 0; j < 8; ++j) g[j] = srcv[(size_t)p[j].x * (NL / 2) + lane];
#pragma unroll
    for (int j = 0; j < 8; ++j) {
      float v = __int_as_float(p[j].y);
      acc.x = fmaf(v, bf2f(g[j].x), acc.x); acc.y = fmaf(v, bf2f(g[j].y), acc.y);
    }
  }
  for (; e + 4 <= e1; e += 4) {
    int2 p[4]; ushort2 g[4];
#pragma unroll
    for (int j = 0; j < 4; ++j) p[j] = ep[e + j];
#pragma unroll
    for (int j = 0; j < 4; ++j) g[j] = srcv[(size_t)p[j].x * (NL / 2) + lane];
#pragma unroll
    for (int j = 0; j < 4; ++j) {
      float v = __int_as_float(p[j].y);
      acc.x = fmaf(v, bf2f(g[j].x), acc.x); acc.y = fmaf(v, bf2f(g[j].y), acc.y);
    }
  }
  for (; e < e1; ++e) {
    int2 p = ep[e];
    float v = __int_as_float(p.y);
    ushort2 g = srcv[(size_t)p.x * (NL / 2) + lane];
    acc.x = fmaf(v, bf2f(g.x), acc.x); acc.y = fmaf(v, bf2f(g.y), acc.y);
  }
  float2 b = ((const float2*)bias)[lane];
  float2 o;
  o.x = fmaxf(acc.x + b.x, 0.f);
  o.y = fmaxf(acc.y + b.y, 0.f);
  out[(size_t)row * (NL / 2) + lane] = o;
}

// ---------------- launch ----------------
extern "C" void kernel_launch(void* const* d_in, const int* in_sizes, int n_in,
                              void* d_out, int out_size, void* d_ws, size_t ws_size,
                              hipStream_t stream) {
  const float* x   = (const float*)d_in[0];
  const int* erow  = (const int*)d_in[1];
  const int* ecol  = (const int*)d_in[2];
  const float* ev  = (const float*)d_in[3];
  const float* W1  = (const float*)d_in[4];
  const float* b1  = (const float*)d_in[5];
  const float* W2  = (const float*)d_in[6];
  const float* b2  = (const float*)d_in[7];

  char* ws = (char*)d_ws;
  unsigned short* xwb = (unsigned short*)(ws + 0);           // 25,600,000 (x@W1 bf16)
  unsigned short* hbf = (unsigned short*)(ws + 25600000);    // 25,600,000 (h bf16)
  unsigned short* hwb = (unsigned short*)(ws + 51200000);    // 12,800,000 (h@W2 bf16)
  unsigned short* w1t = (unsigned short*)(ws + 64000000);    // 262,144
  unsigned short* w2t = (unsigned short*)(ws + 64262144);    // 65,536
  int* rp    = (int*)(ws + 64327680);                        // 200,704
  int* cur   = (int*)(ws + 64528384);                        // 200,704
  int* cnt   = (int*)(ws + 64729088);                        // 200,704
  int* bsum  = (int*)(ws + 64929792);                        // 1,024
  int* bpre  = (int*)(ws + 64930816);                        // 1,024
  int2* ep   = (int2*)(ws + 64931840);                       // 6,400,000

  // CSR build
  hipMemsetAsync(cnt, 0, NN * sizeof(int), stream);
  k_hist<<<NE / 256, 256, 0, stream>>>(erow, cnt, NE);
  k_blocksum<<<NB, 256, 0, stream>>>(cnt, bsum, NN);
  k_scansums<<<1, 256, 0, stream>>>(bsum, bpre, rp, NB, NN);
  k_scanfin<<<NB, 256, 0, stream>>>(cnt, bpre, rp, cur, NN);
  k_scatter<<<NE / 256, 256, 0, stream>>>(erow, ecol, ev, cur, ep, NE);

  // layer 1
  k_transcast<<<NF, NH, 0, stream>>>(W1, w1t, NF, NH);
  k_gemm1<<<dim3(2, (NN + 63) / 64), 256, 0, stream>>>(x, w1t, xwb);
  k_spmm256<<<NN / 4, 256, 0, stream>>>(rp, ep, xwb, b1, (ushort4*)hbf);

  // layer 2
  k_transcast<<<NH, NL, 0, stream>>>(W2, w2t, NH, NL);
  k_gemm2<<<(NN + 63) / 64, 256, 0, stream>>>(hbf, w2t, hwb);
  k_spmm128<<<NN / 4, 256, 0, stream>>>(rp, ep, hwb, b2, (float2*)d_out);
}

// Round 7
// 379.721 us; speedup vs baseline: 1.2670x; 1.2670x over previous
//
#include <hip/hip_runtime.h>
#include <hip/hip_bf16.h>

// GCN encoder: z = relu(A @ relu(A @ (x@W1) + b1) @ W2 + b2)
// R12 = R11 hybrid + the missing sched_barrier(0) order-pinning. R11 failed
// correctness (absmax inf): without fences the compiler may emit A reg-loads
// BEFORE the B gll16s, so my counted vmcnt(4) left B (not A) in flight and the
// next step ds_read hit un-landed LDS (rule #18/#21). R9 passed because every
// phase was fenced. Structure per K-step (order PINNED by sched_barrier(0)):
//   issueB(t+1) |F| loadA(t+3) |F| comp(t) |F| vmcnt(N) lgkmcnt(0) |F| s_bar
// Ledger (B=4ops, A=4ops gemm1 / 2ops gemm2, in-order retire):
//   g1: B0 A0 A1 A2 | B1 A3 | B2 A4 | ... | B7 ; prologue vm(12), steady vm(4)
//   g2: B0 A0 A1 A2 | B1 A3 | B2 | B3 ; prologue vm(6), t0 vm(2), then vm(0)
// A (HBM stream) never touches LDS: rolling 3-deep reg prefetch + cvt_pk.
// B (L2-resident): gll16 swizzled-source LDS double-buffer (R9-verified).

typedef __attribute__((ext_vector_type(8))) short bf16x8;
typedef __attribute__((ext_vector_type(4))) float f32x4;

#define NN 50000
#define NE 800000
#define NF 512
#define NH 256
#define NL 128
#define NB ((NN + 255) / 256)

#define WAIT_VML0() asm volatile("s_waitcnt vmcnt(0) lgkmcnt(0)" ::: "memory")
#define WAIT_VML2() asm volatile("s_waitcnt vmcnt(2) lgkmcnt(0)" ::: "memory")
#define WAIT_VML4() asm volatile("s_waitcnt vmcnt(4) lgkmcnt(0)" ::: "memory")
#define WAIT_VML6() asm volatile("s_waitcnt vmcnt(6) lgkmcnt(0)" ::: "memory")
#define WAIT_VML12() asm volatile("s_waitcnt vmcnt(12) lgkmcnt(0)" ::: "memory")
#define SCHED_FENCE() __builtin_amdgcn_sched_barrier(0)
#define BARRIER() __builtin_amdgcn_s_barrier()

static __device__ __forceinline__ unsigned short f2bf(float f) {
  union { float f; unsigned int u; } v; v.f = f;
  unsigned int r = v.u + 0x7fffu + ((v.u >> 16) & 1u);   // RNE
  return (unsigned short)(r >> 16);
}
static __device__ __forceinline__ float bf2f(unsigned short u) {
  union { unsigned int u; float f; } v; v.u = (unsigned int)u << 16;
  return v.f;
}

// HW packed f32->bf16 (RNE), 2 elems / instruction (no builtin on gfx950).
static __device__ __forceinline__ unsigned int pkbf(float lo, float hi) {
  unsigned int r;
  asm("v_cvt_pk_bf16_f32 %0, %1, %2" : "=v"(r) : "v"(lo), "v"(hi));
  return r;
}
static __device__ __forceinline__ uint4 pk8(float4 a, float4 b) {
  uint4 o;
  o.x = pkbf(a.x, a.y); o.y = pkbf(a.z, a.w);
  o.z = pkbf(b.x, b.y); o.w = pkbf(b.z, b.w);
  return o;
}

// async global->LDS, 16B/lane; LDS dest must be wave-uniform base + lane*16.
static __device__ __forceinline__ void gll16(const void* g, void* l) {
  __builtin_amdgcn_global_load_lds(
      (const __attribute__((address_space(1))) void*)g,
      (__attribute__((address_space(3))) void*)l, 16, 0, 0);
}

// ---------------- CSR build ----------------
extern "C" __global__ void k_hist(const int* __restrict__ rows, int* __restrict__ counts, int n) {
  int i = blockIdx.x * 256 + threadIdx.x;
  if (i < n) atomicAdd(&counts[rows[i]], 1);
}

extern "C" __global__ __launch_bounds__(256) void k_blocksum(
    const int* __restrict__ counts, int* __restrict__ bsum, int n) {
  __shared__ int s[256];
  int t = threadIdx.x;
  int i = blockIdx.x * 256 + t;
  s[t] = (i < n) ? counts[i] : 0;
  __syncthreads();
  for (int off = 128; off > 0; off >>= 1) {
    if (t < off) s[t] += s[t + off];
    __syncthreads();
  }
  if (t == 0) bsum[blockIdx.x] = s[0];
}

extern "C" __global__ __launch_bounds__(256) void k_scansums(
    const int* __restrict__ bsum, int* __restrict__ bpre, int* __restrict__ rp, int nb, int n) {
  __shared__ int s[256];
  int t = threadIdx.x;
  int v = (t < nb) ? bsum[t] : 0;
  s[t] = v;
  __syncthreads();
  for (int off = 1; off < 256; off <<= 1) {
    int u = (t >= off) ? s[t - off] : 0;
    __syncthreads();
    s[t] += u;
    __syncthreads();
  }
  if (t < nb) bpre[t] = s[t] - v;
  if (t == 255) rp[n] = s[255];
}

extern "C" __global__ __launch_bounds__(256) void k_scanfin(
    const int* __restrict__ counts, const int* __restrict__ bpre,
    int* __restrict__ rp, int* __restrict__ cur, int n) {
  __shared__ int s[256];
  int t = threadIdx.x;
  int i = blockIdx.x * 256 + t;
  int c = (i < n) ? counts[i] : 0;
  s[t] = c;
  __syncthreads();
  for (int off = 1; off < 256; off <<= 1) {
    int u = (t >= off) ? s[t - off] : 0;
    __syncthreads();
    s[t] += u;
    __syncthreads();
  }
  if (i < n) {
    int e = bpre[blockIdx.x] + s[t] - c;
    rp[i] = e;
    cur[i] = e;
  }
}

extern "C" __global__ void k_scatter(const int* __restrict__ rows, const int* __restrict__ cols,
    const float* __restrict__ vals, int* __restrict__ cur, int2* __restrict__ ep, int n) {
  int i = blockIdx.x * 256 + threadIdx.x;
  if (i < n) {
    int p = atomicAdd(&cur[rows[i]], 1);
    int2 e; e.x = cols[i]; e.y = __float_as_int(vals[i]);
    ep[p] = e;
  }
}

// ---------------- weight transpose-cast: W [K][N] fp32 -> WT [N][K] bf16 ----------------
extern "C" __global__ void k_transcast(const float* __restrict__ w, unsigned short* __restrict__ wt,
                                       int K, int N) {
  int k = blockIdx.x; int n = threadIdx.x;
  wt[(size_t)n * K + k] = f2bf(w[(size_t)k * N + n]);
}

// ---------------- GEMM1: C[NN][256] = x[NN][512](fp32) * W1T[256][512]^T, bf16 out ----------------
// BM=64 (4 waves x 16 rows), BN=128 (grid.y=2 panels), BK=64, 8 steps.
extern "C" __global__ __launch_bounds__(256) void k_gemm1(
    const float* __restrict__ A, const unsigned short* __restrict__ BT,
    unsigned short* __restrict__ C) {
  __shared__ __align__(16) unsigned short sB[2][128 * 64];
  int tid = threadIdx.x;
  int lane = tid & 63, wid = tid >> 6;
  int l15 = lane & 15, lq = lane >> 4;
  int bm = blockIdx.x * 64, bn = blockIdx.y * 128;
  int swz = l15 & 7;

  int arow = bm + wid * 16 + l15; if (arow >= NN) arow = NN - 1;
  const float* ap = A + (size_t)arow * NF + lq * 8;

  f32x4 acc[8];
#pragma unroll
  for (int i = 0; i < 8; ++i) acc[i] = (f32x4){0.f, 0.f, 0.f, 0.f};

  float4 apf[4][4];   // [slot = t&3][ks*2+half]

  auto issueB = [&](int t) {
#pragma unroll
    for (int j = 0; j < 4; ++j) {
      int u = tid + 256 * j;
      int row = u >> 3, cu = u & 7;
      int g = cu ^ (row & 7);
      gll16(BT + (size_t)(bn + row) * NF + t * 64 + g * 8, &sB[t & 1][u * 8]);
    }
  };
  auto loadA = [&](int t) {
#pragma unroll
    for (int ks = 0; ks < 2; ++ks) {
      apf[t & 3][ks * 2 + 0] = *(const float4*)(ap + t * 64 + ks * 32);
      apf[t & 3][ks * 2 + 1] = *(const float4*)(ap + t * 64 + ks * 32 + 4);
    }
  };
  auto comp = [&](int t) {
#pragma unroll
    for (int ks = 0; ks < 2; ++ks) {
      bf16x8 bfr[8];
#pragma unroll
      for (int nt = 0; nt < 8; ++nt)
        bfr[nt] = *(const bf16x8*)(&sB[t & 1][(nt * 16 + l15) * 64 + ((ks * 4 + lq) ^ swz) * 8]);
      union { uint4 u; bf16x8 v; } cv;
      cv.u = pk8(apf[t & 3][ks * 2], apf[t & 3][ks * 2 + 1]);
      bf16x8 af = cv.v;
#pragma unroll
      for (int nt = 0; nt < 8; ++nt)
        acc[nt] = __builtin_amdgcn_mfma_f32_16x16x32_bf16(af, bfr[nt], acc[nt], 0, 0, 0);
    }
  };

  // prologue: pinned vm order [B0(4), A0,A1,A2(12)] -> vm(12) retires exactly B0
  issueB(0);
  SCHED_FENCE();
  loadA(0); loadA(1); loadA(2);
  SCHED_FENCE();
  WAIT_VML12();
  SCHED_FENCE();
  BARRIER();

#pragma unroll
  for (int t = 0; t < 8; ++t) {
    if (t < 7) { issueB(t + 1); SCHED_FENCE(); }
    if (t < 5) { loadA(t + 3); SCHED_FENCE(); }
    comp(t);
    if (t < 7) {
      SCHED_FENCE();
      // retire through B(t+1); leave A(t+3) (newest 4) in flight while t<5
      if (t < 5) { WAIT_VML4(); } else { WAIT_VML0(); }
      SCHED_FENCE();
      BARRIER();
    }
  }

#pragma unroll
  for (int nt = 0; nt < 8; ++nt) {
#pragma unroll
    for (int r = 0; r < 4; ++r) {
      int gr = bm + wid * 16 + lq * 4 + r;
      if (gr < NN) {
        int gc = bn + nt * 16 + l15;
        C[(size_t)gr * NH + gc] = f2bf(acc[nt][r]);
      }
    }
  }
}

// ---------------- GEMM2: C[NN][128] = h[NN][256](bf16) * W2T[128][256]^T, bf16 out ----------------
// Same skeleton, 4 steps, A already bf16 (no cvt), BN=128 full.
extern "C" __global__ __launch_bounds__(256) void k_gemm2(
    const unsigned short* __restrict__ Ah, const unsigned short* __restrict__ BT,
    unsigned short* __restrict__ C) {
  __shared__ __align__(16) unsigned short sB[2][128 * 64];
  int tid = threadIdx.x;
  int lane = tid & 63, wid = tid >> 6;
  int l15 = lane & 15, lq = lane >> 4;
  int bm = blockIdx.x * 64;
  int swz = l15 & 7;

  int arow = bm + wid * 16 + l15; if (arow >= NN) arow = NN - 1;
  const unsigned short* ap = Ah + (size_t)arow * NH + lq * 8;

  f32x4 acc[8];
#pragma unroll
  for (int i = 0; i < 8; ++i) acc[i] = (f32x4){0.f, 0.f, 0.f, 0.f};

  bf16x8 apf[4][2];   // [slot][ks]

  auto issueB = [&](int t) {
#pragma unroll
    for (int j = 0; j < 4; ++j) {
      int u = tid + 256 * j;
      int row = u >> 3, cu = u & 7;
      int g = cu ^ (row & 7);
      gll16(BT + (size_t)row * NH + t * 64 + g * 8, &sB[t & 1][u * 8]);
    }
  };
  auto loadA = [&](int t) {
#pragma unroll
    for (int ks = 0; ks < 2; ++ks)
      apf[t & 3][ks] = *(const bf16x8*)(ap + t * 64 + ks * 32);
  };
  auto comp = [&](int t) {
#pragma unroll
    for (int ks = 0; ks < 2; ++ks) {
      bf16x8 bfr[8];
#pragma unroll
      for (int nt = 0; nt < 8; ++nt)
        bfr[nt] = *(const bf16x8*)(&sB[t & 1][(nt * 16 + l15) * 64 + ((ks * 4 + lq) ^ swz) * 8]);
      bf16x8 af = apf[t & 3][ks];
#pragma unroll
      for (int nt = 0; nt < 8; ++nt)
        acc[nt] = __builtin_amdgcn_mfma_f32_16x16x32_bf16(af, bfr[nt], acc[nt], 0, 0, 0);
    }
  };

  // prologue: pinned [B0(4), A0,A1,A2(6)] -> vm(6) retires exactly B0
  issueB(0);
  SCHED_FENCE();
  loadA(0); loadA(1); loadA(2);
  SCHED_FENCE();
  WAIT_VML6();
  SCHED_FENCE();
  BARRIER();

#pragma unroll
  for (int t = 0; t < 4; ++t) {
    if (t < 3) { issueB(t + 1); SCHED_FENCE(); }
    if (t < 1) { loadA(t + 3); SCHED_FENCE(); }
    comp(t);
    if (t < 3) {
      SCHED_FENCE();
      if (t < 1) { WAIT_VML2(); } else { WAIT_VML0(); }
      SCHED_FENCE();
      BARRIER();
    }
  }

#pragma unroll
  for (int nt = 0; nt < 8; ++nt) {
#pragma unroll
    for (int r = 0; r < 4; ++r) {
      int gr = bm + wid * 16 + lq * 4 + r;
      if (gr < NN) {
        int gc = nt * 16 + l15;
        C[(size_t)gr * NL + gc] = f2bf(acc[nt][r]);
      }
    }
  }
}

// ---------------- SpMM (CSR row-gather), bf16 src, unroll-8/4/1, fused bias+relu ----------------
extern "C" __global__ __launch_bounds__(256) void k_spmm256(
    const int* __restrict__ rp, const int2* __restrict__ ep,
    const unsigned short* __restrict__ src, const float* __restrict__ bias,
    ushort4* __restrict__ out) {
  int row = blockIdx.x * 4 + (threadIdx.x >> 6);
  int lane = threadIdx.x & 63;
  if (row >= NN) return;
  int e0 = __builtin_amdgcn_readfirstlane(rp[row]);
  int e1 = __builtin_amdgcn_readfirstlane(rp[row + 1]);
  const ushort4* srcv = (const ushort4*)src;
  float4 acc = {0.f, 0.f, 0.f, 0.f};
  int e = e0;
  for (; e + 8 <= e1; e += 8) {
    int2 p[8]; ushort4 g[8];
#pragma unroll
    for (int j = 0; j < 8; ++j) p[j] = ep[e + j];
#pragma unroll
    for (int j = 0; j < 8; ++j) g[j] = srcv[(size_t)p[j].x * (NH / 4) + lane];
#pragma unroll
    for (int j = 0; j < 8; ++j) {
      float v = __int_as_float(p[j].y);
      acc.x = fmaf(v, bf2f(g[j].x), acc.x); acc.y = fmaf(v, bf2f(g[j].y), acc.y);
      acc.z = fmaf(v, bf2f(g[j].z), acc.z); acc.w = fmaf(v, bf2f(g[j].w), acc.w);
    }
  }
  for (; e + 4 <= e1; e += 4) {
    int2 p[4]; ushort4 g[4];
#pragma unroll
    for (int j = 0; j < 4; ++j) p[j] = ep[e + j];
#pragma unroll
    for (int j = 0; j < 4; ++j) g[j] = srcv[(size_t)p[j].x * (NH / 4) + lane];
#pragma unroll
    for (int j = 0; j < 4; ++j) {
      float v = __int_as_float(p[j].y);
      acc.x = fmaf(v, bf2f(g[j].x), acc.x); acc.y = fmaf(v, bf2f(g[j].y), acc.y);
      acc.z = fmaf(v, bf2f(g[j].z), acc.z); acc.w = fmaf(v, bf2f(g[j].w), acc.w);
    }
  }
  for (; e < e1; ++e) {
    int2 p = ep[e];
    float v = __int_as_float(p.y);
    ushort4 g = srcv[(size_t)p.x * (NH / 4) + lane];
    acc.x = fmaf(v, bf2f(g.x), acc.x); acc.y = fmaf(v, bf2f(g.y), acc.y);
    acc.z = fmaf(v, bf2f(g.z), acc.z); acc.w = fmaf(v, bf2f(g.w), acc.w);
  }
  float4 b = ((const float4*)bias)[lane];
  ushort4 o;
  o.x = f2bf(fmaxf(acc.x + b.x, 0.f));
  o.y = f2bf(fmaxf(acc.y + b.y, 0.f));
  o.z = f2bf(fmaxf(acc.z + b.z, 0.f));
  o.w = f2bf(fmaxf(acc.w + b.w, 0.f));
  out[(size_t)row * (NH / 4) + lane] = o;
}

extern "C" __global__ __launch_bounds__(256) void k_spmm128(
    const int* __restrict__ rp, const int2* __restrict__ ep,
    const unsigned short* __restrict__ src, const float* __restrict__ bias,
    float2* __restrict__ out) {
  int row = blockIdx.x * 4 + (threadIdx.x >> 6);
  int lane = threadIdx.x & 63;
  if (row >= NN) return;
  int e0 = __builtin_amdgcn_readfirstlane(rp[row]);
  int e1 = __builtin_amdgcn_readfirstlane(rp[row + 1]);
  const ushort2* srcv = (const ushort2*)src;
  float2 acc = {0.f, 0.f};
  int e = e0;
  for (; e + 8 <= e1; e += 8) {
    int2 p[8]; ushort2 g[8];
#pragma unroll
    for (int j = 0; j < 8; ++j) p[j] = ep[e + j];
#pragma unroll
    for (int j = 0; j < 8; ++j) g[j] = srcv[(size_t)p[j].x * (NL / 2) + lane];
#pragma unroll
    for (int j = 0; j < 8; ++j) {
      float v = __int_as_float(p[j].y);
      acc.x = fmaf(v, bf2f(g[j].x), acc.x); acc.y = fmaf(v, bf2f(g[j].y), acc.y);
    }
  }
  for (; e + 4 <= e1; e += 4) {
    int2 p[4]; ushort2 g[4];
#pragma unroll
    for (int j = 0; j < 4; ++j) p[j] = ep[e + j];
#pragma unroll
    for (int j = 0; j < 4; ++j) g[j] = srcv[(size_t)p[j].x * (NL / 2) + lane];
#pragma unroll
    for (int j = 0; j < 4; ++j) {
      float v = __int_as_float(p[j].y);
      acc.x = fmaf(v, bf2f(g[j].x), acc.x); acc.y = fmaf(v, bf2f(g[j].y), acc.y);
    }
  }
  for (; e < e1; ++e) {
    int2 p = ep[e];
    float v = __int_as_float(p.y);
    ushort2 g = srcv[(size_t)p.x * (NL / 2) + lane];
    acc.x = fmaf(v, bf2f(g.x), acc.x); acc.y = fmaf(v, bf2f(g.y), acc.y);
  }
  float2 b = ((const float2*)bias)[lane];
  float2 o;
  o.x = fmaxf(acc.x + b.x, 0.f);
  o.y = fmaxf(acc.y + b.y, 0.f);
  out[(size_t)row * (NL / 2) + lane] = o;
}

// ---------------- launch ----------------
extern "C" void kernel_launch(void* const* d_in, const int* in_sizes, int n_in,
                              void* d_out, int out_size, void* d_ws, size_t ws_size,
                              hipStream_t stream) {
  const float* x   = (const float*)d_in[0];
  const int* erow  = (const int*)d_in[1];
  const int* ecol  = (const int*)d_in[2];
  const float* ev  = (const float*)d_in[3];
  const float* W1  = (const float*)d_in[4];
  const float* b1  = (const float*)d_in[5];
  const float* W2  = (const float*)d_in[6];
  const float* b2  = (const float*)d_in[7];

  char* ws = (char*)d_ws;
  unsigned short* xwb = (unsigned short*)(ws + 0);           // 25,600,000 (x@W1 bf16)
  unsigned short* hbf = (unsigned short*)(ws + 25600000);    // 25,600,000 (h bf16)
  unsigned short* hwb = (unsigned short*)(ws + 51200000);    // 12,800,000 (h@W2 bf16)
  unsigned short* w1t = (unsigned short*)(ws + 64000000);    // 262,144
  unsigned short* w2t = (unsigned short*)(ws + 64262144);    // 65,536
  int* rp    = (int*)(ws + 64327680);                        // 200,704
  int* cur   = (int*)(ws + 64528384);                        // 200,704
  int* cnt   = (int*)(ws + 64729088);                        // 200,704
  int* bsum  = (int*)(ws + 64929792);                        // 1,024
  int* bpre  = (int*)(ws + 64930816);                        // 1,024
  int2* ep   = (int2*)(ws + 64931840);                       // 6,400,000

  // CSR build
  hipMemsetAsync(cnt, 0, NN * sizeof(int), stream);
  k_hist<<<NE / 256, 256, 0, stream>>>(erow, cnt, NE);
  k_blocksum<<<NB, 256, 0, stream>>>(cnt, bsum, NN);
  k_scansums<<<1, 256, 0, stream>>>(bsum, bpre, rp, NB, NN);
  k_scanfin<<<NB, 256, 0, stream>>>(cnt, bpre, rp, cur, NN);
  k_scatter<<<NE / 256, 256, 0, stream>>>(erow, ecol, ev, cur, ep, NE);

  // layer 1
  k_transcast<<<NF, NH, 0, stream>>>(W1, w1t, NF, NH);
  k_gemm1<<<dim3((NN + 63) / 64, NH / 128), 256, 0, stream>>>(x, w1t, xwb);
  k_spmm256<<<NN / 4, 256, 0, stream>>>(rp, ep, xwb, b1, (ushort4*)hbf);

  // layer 2
  k_transcast<<<NH, NL, 0, stream>>>(W2, w2t, NH, NL);
  k_gemm2<<<(NN + 63) / 64, 256, 0, stream>>>(hbf, w2t, hwb);
  k_spmm128<<<NN / 4, 256, 0, stream>>>(rp, ep, hwb, b2, (float2*)d_out);
}